// Round 9
// baseline (105.862 us; speedup 1.0000x reference)
//
#include <hip/hip_runtime.h>
#include <math.h>

#define N_S 2
#define N_V 4
#define DQ  64
#define HH  256
#define WW  320
#define HW  (HH * WW)            // 81920 px per (nv,d) slice
#define SPLIT 8                  // chunks per slice
#define CHUNK_PX (HW / SPLIT)    // 10240 px per block
#define XY_ITERS (CHUNK_PX / 512)   // 20 (2 px/thread/iter)
#define MK_ITERS (CHUNK_PX / 1024)  // 10 (4 px/thread/iter)

#define XY_BLOCKS (N_S * N_V * DQ * SPLIT)   // 4096
#define TOT_BLOCKS (2 * XY_BLOCKS)           // 8192

typedef float f32x4 __attribute__((ext_vector_type(4)));

// Per-block camera algebra with depth folded in:
// proj(X,Y) = Q·[X,Y,1] + (b)   where Q = depth * Ksrc·R_rel·Kd^-1
__device__ __forceinline__ void camera_setup_folded(
    const float* __restrict__ Kd, const float* __restrict__ Ed,
    const float* __restrict__ Ks, const float* __restrict__ Es,
    int nv, int n, int d,
    float Q[3][3], float cvec[3])
{
    // inv(Ed): rigid [R|t] -> [R^T | -R^T t]
    const float* E = Ed + n * 16;
    float Ri[3][3], ti[3];
    #pragma unroll
    for (int r = 0; r < 3; ++r)
        #pragma unroll
        for (int c = 0; c < 3; ++c)
            Ri[r][c] = E[c * 4 + r];
    #pragma unroll
    for (int r = 0; r < 3; ++r)
        ti[r] = -(Ri[r][0] * E[3] + Ri[r][1] * E[7] + Ri[r][2] * E[11]);

    // T = Es @ inv(Ed)
    const float* S = Es + nv * 16;
    float Tr[3][3], Tt[3];
    #pragma unroll
    for (int r = 0; r < 3; ++r) {
        #pragma unroll
        for (int c = 0; c < 3; ++c)
            Tr[r][c] = S[r*4+0]*Ri[0][c] + S[r*4+1]*Ri[1][c] + S[r*4+2]*Ri[2][c];
        Tt[r] = S[r*4+0]*ti[0] + S[r*4+1]*ti[1] + S[r*4+2]*ti[2] + S[r*4+3];
    }

    // A = Ksrc @ Tr ; b = Ksrc @ Tt
    const float* Kv = Ks + nv * 9;
    float Am[3][3], bm[3];
    #pragma unroll
    for (int r = 0; r < 3; ++r) {
        #pragma unroll
        for (int c = 0; c < 3; ++c)
            Am[r][c] = Kv[r*3+0]*Tr[0][c] + Kv[r*3+1]*Tr[1][c] + Kv[r*3+2]*Tr[2][c];
        bm[r] = Kv[r*3+0]*Tt[0] + Kv[r*3+1]*Tt[1] + Kv[r*3+2]*Tt[2];
    }

    // inv(Kd) via adjugate/det
    float IK[3][3];
    {
        const float* Km = Kd + n * 9;
        float a=Km[0],b=Km[1],c=Km[2],dd=Km[3],e=Km[4],f=Km[5],g=Km[6],hh=Km[7],k=Km[8];
        float det = a*(e*k - f*hh) - b*(dd*k - f*g) + c*(dd*hh - e*g);
        float inv = 1.0f / det;
        IK[0][0] =  (e*k - f*hh) * inv;
        IK[0][1] = -(b*k - c*hh) * inv;
        IK[0][2] =  (b*f - c*e) * inv;
        IK[1][0] = -(dd*k - f*g) * inv;
        IK[1][1] =  (a*k - c*g) * inv;
        IK[1][2] = -(a*f - c*dd) * inv;
        IK[2][0] =  (dd*hh - e*g) * inv;
        IK[2][1] = -(a*hh - b*g) * inv;
        IK[2][2] =  (a*e - b*dd) * inv;
    }

    const float step = (float)(9.5 / 63.0);
    float depth = 0.5f + (float)d * step;
    #pragma unroll
    for (int r = 0; r < 3; ++r) {
        #pragma unroll
        for (int c = 0; c < 3; ++c)
            Q[r][c] = depth * (Am[r][0]*IK[0][c] + Am[r][1]*IK[1][c] + Am[r][2]*IK[2][c]);
        cvec[r] = Q[r][2] + bm[r];    // fold the homogeneous-1 column
    }
}

__global__ __launch_bounds__(256) void stream_kernel(
    const float* __restrict__ Kd, const float* __restrict__ Ed,
    const float* __restrict__ Ks, const float* __restrict__ Es,
    float* __restrict__ out)
{
    int bid = blockIdx.x;
    bool is_mask = (bid >= XY_BLOCKS);
    int rb = is_mask ? (bid - XY_BLOCKS) : bid;

    int chunk = rb % SPLIT;
    int d     = (rb / SPLIT) % DQ;
    int nv    = rb / (SPLIT * DQ);
    int n     = nv >> 2;

    float Q[3][3], cv[3];
    camera_setup_folded(Kd, Ed, Ks, Es, nv, n, d, Q, cv);
    float Q00=Q[0][0], Q01=Q[0][1], c0=cv[0];
    float Q10=Q[1][0], Q11=Q[1][1], c1=cv[1];
    float Q20=Q[2][0], Q21=Q[2][1], c2=cv[2];

    size_t slice = (size_t)nv * DQ + (size_t)d;

    if (!is_mask) {
        // ---- xy role: 2 px/thread, block streams 80 KB contiguous ----
        float* __restrict__ xyp = out + (slice * (size_t)HW + (size_t)chunk * CHUNK_PX) * 2;
        int t2 = threadIdx.x * 2;
        int pix0 = chunk * CHUNK_PX + t2;   // within slice
        int h = pix0 / WW;
        int w = pix0 - h * WW;

        #pragma unroll 4
        for (int j = 0; j < XY_ITERS; ++j) {
            float X = (float)w, Y = (float)h;
            float px0 = Q00*X + Q01*Y + c0;
            float py0 = Q10*X + Q11*Y + c1;
            float pz0 = Q20*X + Q21*Y + c2;
            float px1 = px0 + Q00, py1 = py0 + Q10, pz1 = pz0 + Q20;

            float zs0 = (fabsf(pz0) < 1e-8f) ? 1e-8f : pz0;
            float zs1 = (fabsf(pz1) < 1e-8f) ? 1e-8f : pz1;
            float r0 = __builtin_amdgcn_rcpf(zs0); r0 = r0 * (2.0f - zs0 * r0);
            float r1 = __builtin_amdgcn_rcpf(zs1); r1 = r1 * (2.0f - zs1 * r1);

            f32x4 xyv;
            xyv.x = px0 * r0; xyv.y = py0 * r0;
            xyv.z = px1 * r1; xyv.w = py1 * r1;
            __builtin_nontemporal_store(xyv, (f32x4*)(xyp + (size_t)(j * 512 + t2) * 2));

            // advance 512 px: +1 row +192 cols (WW=320)
            w += 192; h += 1;
            if (w >= WW) { w -= WW; h += 1; }
        }
    } else {
        // ---- mask role: 4 px/thread, block streams 40 KB contiguous ----
        float* __restrict__ mp = out + (size_t)N_S * N_V * DQ * HW * 2
                               + slice * (size_t)HW + (size_t)chunk * CHUNK_PX;
        int t4 = threadIdx.x * 4;
        int pix0 = chunk * CHUNK_PX + t4;
        int h = pix0 / WW;
        int w = pix0 - h * WW;

        #pragma unroll 2
        for (int j = 0; j < MK_ITERS; ++j) {
            float X = (float)w, Y = (float)h;
            float px = Q00*X + Q01*Y + c0;
            float py = Q10*X + Q11*Y + c1;
            float pz = Q20*X + Q21*Y + c2;

            f32x4 mv;
            #pragma unroll
            for (int p = 0; p < 4; ++p) {
                float zs = (fabsf(pz) < 1e-8f) ? 1e-8f : pz;
                float r  = __builtin_amdgcn_rcpf(zs); r = r * (2.0f - zs * r);
                float x = px * r, y = py * r;
                mv[p] = (x >= 0.0f && x <= (float)(WW-1) &&
                         y >= 0.0f && y <= (float)(HH-1) && pz > 0.0f) ? 1.0f : 0.0f;
                px += Q00; py += Q10; pz += Q20;   // next pixel in row-major order
            }
            __builtin_nontemporal_store(mv, (f32x4*)(mp + (size_t)(j * 1024 + t4)));

            // advance 1024 px: +3 rows +64 cols (WW=320)
            w += 64; h += 3;
            if (w >= WW) { w -= WW; h += 1; }
        }
    }
}

extern "C" void kernel_launch(void* const* d_in, const int* in_sizes, int n_in,
                              void* d_out, int out_size, void* d_ws, size_t ws_size,
                              hipStream_t stream) {
    const float* Kd = (const float*)d_in[0];   // (N,1,3,3)
    const float* Ed = (const float*)d_in[1];   // (N,1,4,4)
    const float* Ks = (const float*)d_in[2];   // (N,V,3,3)
    const float* Es = (const float*)d_in[3];   // (N,V,4,4)

    hipLaunchKernelGGL(stream_kernel, dim3(TOT_BLOCKS), dim3(256), 0, stream,
                       Kd, Ed, Ks, Es, (float*)d_out);
}